// Round 18
// baseline (123.109 us; speedup 1.0000x reference)
//
#include <hip/hip_runtime.h>
#include <limits.h>

#define SEQ   200
#define BATCH 1024
#define DIM   300
#define HID   600
#define VOCAB 100000

#define NQ    4              // sorted-list quarters (gather grid.y)
#define NBKT  64             // buckets for approximate sort

#define BW    4              // batches per wave (mlp) — r14-proven
#define JCH   12             // j-chunks across blockIdx.y (mlp)
#define JPER  (HID / JCH)    // 50 j per chunk

#define HIDDEN_ELEMS (BATCH * HID)               // 614400
#define HIDDEN_BYTES ((size_t)HIDDEN_ELEMS * 4)  // 2,457,600

// ws layout
#define SORT_BYTES  ((size_t)BATCH * 256 * 4)    // 1,048,576
#define OFF_NK      SORT_BYTES
#define OFF_HID4    (SORT_BYTES + 65536)         // padded
#define OFF_HIDDEN  (OFF_HID4 + 4 * HIDDEN_BYTES)
#define OFF_W1B     (OFF_HIDDEN + HIDDEN_BYTES)  // bf16 W1 (720 KB)

// ---------- Kernel A: dedup + 64-bucket sort (+ fused out-init) ----------
__global__ __launch_bounds__(256) void sort_kernel(
    const int* __restrict__ tokens,
    int* __restrict__ sorted_g,
    int* __restrict__ nk_g,
    float* __restrict__ out,
    const float* __restrict__ b2) {
  const int b    = blockIdx.x;
  const int tid  = threadIdx.x;
  const int w    = tid >> 6;
  const int lane = tid & 63;

  __shared__ int hist[NBKT];
  __shared__ int base[NBKT];
  __shared__ int cur[NBKT];
  __shared__ int stok[SEQ];
  __shared__ int keepf[SEQ];
  __shared__ int wsum[4];

  if (tid == 0) out[b] = b2[0];          // fused out-init (one block per b)

  if (tid < NBKT) { hist[tid] = 0; cur[tid] = 0; }
  __syncthreads();

  int t = 0, bk = 0;
  if (tid < SEQ) {
    t  = tokens[tid * BATCH + b];
    bk = (int)((unsigned)t * (unsigned)NBKT / (unsigned)VOCAB);
    atomicAdd(&hist[bk], 1);
  }
  __syncthreads();

  if (tid < NBKT) {            // wave 0: exclusive scan of 64 buckets
    const int v = hist[tid];
    int incl = v;
#pragma unroll
    for (int off = 1; off < NBKT; off <<= 1) {
      const int n = __shfl_up(incl, off, 64);
      if (lane >= off) incl += n;
    }
    base[tid] = incl - v;
  }
  __syncthreads();

  int pos = -1;
  if (tid < SEQ) {
    pos = base[bk] + atomicAdd(&cur[bk], 1);
    stok[pos] = t;
  }
  __syncthreads();

  if (tid < SEQ) {             // dedup within bucket
    int kf = 1;
    const int b0 = base[bk];
    for (int j = b0; j < pos; ++j) {
      if (stok[j] == t) { kf = 0; break; }
    }
    keepf[pos] = kf;
  }
  __syncthreads();

  // order-preserving compaction: two-level scan over 200 keep flags
  const int val = (tid < SEQ) ? keepf[tid] : 0;
  int incl = val;
#pragma unroll
  for (int off = 1; off < 64; off <<= 1) {
    const int n = __shfl_up(incl, off, 64);
    if (lane >= off) incl += n;
  }
  if (lane == 63) wsum[w] = incl;
  __syncthreads();

  int prefix = 0;
  for (int q = 0; q < w; ++q) prefix += wsum[q];
  if (tid < SEQ && val) sorted_g[b * 256 + prefix + incl - val] = stok[tid];
  if (tid == 0) nk_g[b] = wsum[0] + wsum[1] + wsum[2] + wsum[3];
}

// ---------- Kernel A2: W1 -> bf16 (RNE), 720 KB out ----------------------
__global__ __launch_bounds__(256) void convert_w1_kernel(
    const float2* __restrict__ w1f2,
    unsigned int* __restrict__ w1b2) {
  const int i = blockIdx.x * 256 + threadIdx.x;   // pair index
  if (i < HID * HID / 2) {
    const float2 f = w1f2[i];
    const unsigned int ux = __float_as_uint(f.x);
    const unsigned int uy = __float_as_uint(f.y);
    const unsigned int bx = (ux + 0x7FFFu + ((ux >> 16) & 1u)) >> 16;
    const unsigned int by = (uy + 0x7FFFu + ((uy >> 16) & 1u)) >> 16;
    w1b2[i] = bx | (by << 16);
  }
}

// ---------- Kernel B: sorted fp32 gather (LDS-free, barrier-free) --------
__global__ __launch_bounds__(192) void embed_gather_kernel(
    const int* __restrict__ sorted_g,
    const int* __restrict__ nk_g,
    const float* __restrict__ lut,
    const float* __restrict__ slut,
    float* __restrict__ hid4) {
  const int b   = blockIdx.x;
  const int q   = blockIdx.y;
  const int tid = threadIdx.x;

  const int nk = nk_g[b];
  const int i0 = (q * nk) / NQ;
  const int i1 = ((q + 1) * nk) / NQ;

  const int tab_i = tid / 75;            // 0 -> lut, 1 -> slut, 2 -> idle
  const int slot  = tid % 75;
  if (tab_i < 2) {
    const float* __restrict__ tab = tab_i ? slut : lut;
    const int* __restrict__ rows = sorted_g + b * 256;
    float4 a = make_float4(0.f, 0.f, 0.f, 0.f);
#pragma unroll 8
    for (int i = i0; i < i1; ++i) {      // ascending bucket order
      const float4 v = ((const float4*)(tab + (size_t)rows[i] * DIM))[slot];
      a.x += v.x; a.y += v.y; a.z += v.z; a.w += v.w;
    }
    float* dst = hid4 + ((size_t)q * BATCH + b) * HID + tab_i * DIM;
    ((float4*)dst)[slot] = a;
  }
}

// ---------- Kernel C: hidden = sum of 4 partials (r14-proven) ------------
__global__ __launch_bounds__(256) void combine_kernel(
    const float* __restrict__ hid4, float* __restrict__ hidden) {
  const int i = blockIdx.x * 256 + threadIdx.x;   // float4 index
  const int n4 = HIDDEN_ELEMS / 4;                // 153600
  if (i < n4) {
    const float4* p = (const float4*)hid4;
    const float4 a = p[i];
    const float4 b = p[i + n4];
    const float4 c = p[i + 2 * n4];
    const float4 d = p[i + 3 * n4];
    float4 s;
    s.x = (a.x + b.x) + (c.x + d.x);
    s.y = (a.y + b.y) + (c.y + d.y);
    s.z = (a.z + b.z) + (c.z + d.z);
    s.w = (a.w + b.w) + (c.w + d.w);
    ((float4*)hidden)[i] = s;
  }
}

// ---------- Kernel D: MLP — 4 batches/wave, bf16 W1 (L2 bytes halved) ----
template <int CTRL>
__device__ __forceinline__ float dpp_add(float x) {
  const int y = __builtin_amdgcn_update_dpp(
      0, __float_as_int(x), CTRL, 0xf, 0xf, true);
  return x + __int_as_float(y);
}

__device__ __forceinline__ float wave_sum(float h) {
  h = dpp_add<0x111>(h);   // row_shr:1
  h = dpp_add<0x112>(h);   // row_shr:2
  h = dpp_add<0x114>(h);   // row_shr:4
  h = dpp_add<0x118>(h);   // row_shr:8
  h = dpp_add<0x142>(h);   // row_bcast:15
  h = dpp_add<0x143>(h);   // row_bcast:31  -> lane 63 holds full sum
  return h;
}

__device__ __forceinline__ float bf2f(unsigned int u) {
  return __uint_as_float(u << 16);
}

__global__ __launch_bounds__(256) void mlp_kernel(
    const float* __restrict__ hidden,
    const ushort* __restrict__ w1b,
    const float* __restrict__ b1,
    const float* __restrict__ W2,
    float* __restrict__ out) {
  const int wave = threadIdx.x >> 6;
  const int lane = threadIdx.x & 63;
  const int b0   = (blockIdx.x * 4 + wave) * BW;
  const int j0   = blockIdx.y * JPER;

  // preload 4 hidden rows: k = lane + 64*i (600 = 64*9 + 24)
  float a[BW][10];
#pragma unroll
  for (int bb = 0; bb < BW; ++bb) {
    const float* __restrict__ hb = hidden + (size_t)(b0 + bb) * HID;
#pragma unroll
    for (int i = 0; i < 9; ++i) a[bb][i] = hb[lane + 64 * i];
    a[bb][9] = (lane < 24) ? hb[lane + 576] : 0.f;
  }

  float acc[BW] = {0.f, 0.f, 0.f, 0.f};

#pragma unroll 2
  for (int jj = 0; jj < JPER; ++jj) {
    const int j = j0 + jj;
    const ushort* __restrict__ wr = w1b + (size_t)j * HID;
    float d0 = 0.f, d1 = 0.f, d2 = 0.f, d3 = 0.f;
#pragma unroll
    for (int i = 0; i < 9; ++i) {
      const float w = bf2f(wr[lane + 64 * i]);
      d0 += a[0][i] * w;
      d1 += a[1][i] * w;
      d2 += a[2][i] * w;
      d3 += a[3][i] * w;
    }
    {
      const float w = (lane < 24) ? bf2f(wr[lane + 576]) : 0.f;
      d0 += a[0][9] * w;
      d1 += a[1][9] * w;
      d2 += a[2][9] * w;
      d3 += a[3][9] * w;
    }
    // 4 independent 6-step DPP chains (ILP hides DPP latency)
    d0 = wave_sum(d0); d1 = wave_sum(d1);
    d2 = wave_sum(d2); d3 = wave_sum(d3);
    // branch-free epilogue: only lane 63's acc is ever consumed
    const float b1j = b1[j];
    const float w2j = W2[j];
    acc[0] += fmaxf(d0 + b1j, 0.f) * w2j;
    acc[1] += fmaxf(d1 + b1j, 0.f) * w2j;
    acc[2] += fmaxf(d2 + b1j, 0.f) * w2j;
    acc[3] += fmaxf(d3 + b1j, 0.f) * w2j;
  }

  if (lane == 63) {
#pragma unroll
    for (int bb = 0; bb < BW; ++bb) atomicAdd(&out[b0 + bb], acc[bb]);
  }
}

extern "C" void kernel_launch(void* const* d_in, const int* in_sizes, int n_in,
                              void* d_out, int out_size, void* d_ws, size_t ws_size,
                              hipStream_t stream) {
  const int*   tokens = (const int*)  d_in[0];
  const float* lut    = (const float*)d_in[1];
  const float* slut   = (const float*)d_in[2];
  const float* W1     = (const float*)d_in[3];
  const float* b1     = (const float*)d_in[4];
  const float* W2     = (const float*)d_in[5];
  const float* b2     = (const float*)d_in[6];
  float* out = (float*)d_out;

  int*    sorted_g = (int*)d_ws;
  int*    nk_g     = (int*)((char*)d_ws + OFF_NK);
  float*  hid4     = (float*)((char*)d_ws + OFF_HID4);
  float*  hidden   = (float*)((char*)d_ws + OFF_HIDDEN);
  ushort* w1b      = (ushort*)((char*)d_ws + OFF_W1B);

  sort_kernel<<<BATCH, 256, 0, stream>>>(tokens, sorted_g, nk_g, out, b2);
  convert_w1_kernel<<<(HID * HID / 2 + 255) / 256, 256, 0, stream>>>(
      (const float2*)W1, (unsigned int*)w1b);
  embed_gather_kernel<<<dim3(BATCH, NQ), 192, 0, stream>>>(
      sorted_g, nk_g, lut, slut, hid4);
  combine_kernel<<<(HIDDEN_ELEMS / 4 + 255) / 256, 256, 0, stream>>>(
      hid4, hidden);
  mlp_kernel<<<dim3(BATCH / (4 * BW), JCH), 256, 0, stream>>>(
      hidden, w1b, b1, W2, out);
}

// Round 19
// 116.408 us; speedup vs baseline: 1.0576x; 1.0576x over previous
//
#include <hip/hip_runtime.h>
#include <limits.h>

#define SEQ   200
#define BATCH 1024
#define DIM   300
#define HID   600
#define VOCAB 100000

#define NQ    4              // sorted-list quarters (gather grid.y)
#define NBKT  64             // buckets for approximate sort

#define BW    4              // batches per wave (mlp) — r14-proven
#define JCH   12             // j-chunks across blockIdx.y (mlp)
#define JPER  (HID / JCH)    // 50 j per chunk

#define HIDDEN_ELEMS (BATCH * HID)               // 614400
#define HIDDEN_BYTES ((size_t)HIDDEN_ELEMS * 4)  // 2,457,600

// ws layout
#define SORT_BYTES  ((size_t)BATCH * 256 * 4)    // 1,048,576
#define OFF_NK      SORT_BYTES
#define OFF_HID4    (SORT_BYTES + 65536)         // padded
#define OFF_HIDDEN  (OFF_HID4 + 4 * HIDDEN_BYTES)

// ---------- Kernel A: dedup + 64-bucket sort (+ fused out-init) ----------
__global__ __launch_bounds__(256) void sort_kernel(
    const int* __restrict__ tokens,
    int* __restrict__ sorted_g,
    int* __restrict__ nk_g,
    float* __restrict__ out,
    const float* __restrict__ b2) {
  const int b    = blockIdx.x;
  const int tid  = threadIdx.x;
  const int w    = tid >> 6;
  const int lane = tid & 63;

  __shared__ int hist[NBKT];
  __shared__ int base[NBKT];
  __shared__ int cur[NBKT];
  __shared__ int stok[SEQ];
  __shared__ int keepf[SEQ];
  __shared__ int wsum[4];

  if (tid == 0) out[b] = b2[0];          // fused out-init (one block per b)

  if (tid < NBKT) { hist[tid] = 0; cur[tid] = 0; }
  __syncthreads();

  int t = 0, bk = 0;
  if (tid < SEQ) {
    t  = tokens[tid * BATCH + b];
    bk = (int)((unsigned)t * (unsigned)NBKT / (unsigned)VOCAB);
    atomicAdd(&hist[bk], 1);
  }
  __syncthreads();

  if (tid < NBKT) {            // wave 0: exclusive scan of 64 buckets
    const int v = hist[tid];
    int incl = v;
#pragma unroll
    for (int off = 1; off < NBKT; off <<= 1) {
      const int n = __shfl_up(incl, off, 64);
      if (lane >= off) incl += n;
    }
    base[tid] = incl - v;
  }
  __syncthreads();

  int pos = -1;
  if (tid < SEQ) {
    pos = base[bk] + atomicAdd(&cur[bk], 1);
    stok[pos] = t;
  }
  __syncthreads();

  if (tid < SEQ) {             // dedup within bucket
    int kf = 1;
    const int b0 = base[bk];
    for (int j = b0; j < pos; ++j) {
      if (stok[j] == t) { kf = 0; break; }
    }
    keepf[pos] = kf;
  }
  __syncthreads();

  // order-preserving compaction: two-level scan over 200 keep flags
  const int val = (tid < SEQ) ? keepf[tid] : 0;
  int incl = val;
#pragma unroll
  for (int off = 1; off < 64; off <<= 1) {
    const int n = __shfl_up(incl, off, 64);
    if (lane >= off) incl += n;
  }
  if (lane == 63) wsum[w] = incl;
  __syncthreads();

  int prefix = 0;
  for (int q = 0; q < w; ++q) prefix += wsum[q];
  if (tid < SEQ && val) sorted_g[b * 256 + prefix + incl - val] = stok[tid];
  if (tid == 0) nk_g[b] = wsum[0] + wsum[1] + wsum[2] + wsum[3];
}

// ---------- Kernel B: sorted fp32 gather (LDS-free, barrier-free) --------
__global__ __launch_bounds__(192) void embed_gather_kernel(
    const int* __restrict__ sorted_g,
    const int* __restrict__ nk_g,
    const float* __restrict__ lut,
    const float* __restrict__ slut,
    float* __restrict__ hid4) {
  const int b   = blockIdx.x;
  const int q   = blockIdx.y;
  const int tid = threadIdx.x;

  const int nk = nk_g[b];
  const int i0 = (q * nk) / NQ;
  const int i1 = ((q + 1) * nk) / NQ;

  const int tab_i = tid / 75;            // 0 -> lut, 1 -> slut, 2 -> idle
  const int slot  = tid % 75;
  if (tab_i < 2) {
    const float* __restrict__ tab = tab_i ? slut : lut;
    const int* __restrict__ rows = sorted_g + b * 256;
    float4 a = make_float4(0.f, 0.f, 0.f, 0.f);
#pragma unroll 8
    for (int i = i0; i < i1; ++i) {      // ascending bucket order
      const float4 v = ((const float4*)(tab + (size_t)rows[i] * DIM))[slot];
      a.x += v.x; a.y += v.y; a.z += v.z; a.w += v.w;
    }
    float* dst = hid4 + ((size_t)q * BATCH + b) * HID + tab_i * DIM;
    ((float4*)dst)[slot] = a;
  }
}

// ---------- Kernel C: hidden = sum of 4 partials (r14-proven) ------------
__global__ __launch_bounds__(256) void combine_kernel(
    const float* __restrict__ hid4, float* __restrict__ hidden) {
  const int i = blockIdx.x * 256 + threadIdx.x;   // float4 index
  const int n4 = HIDDEN_ELEMS / 4;                // 153600
  if (i < n4) {
    const float4* p = (const float4*)hid4;
    const float4 a = p[i];
    const float4 b = p[i + n4];
    const float4 c = p[i + 2 * n4];
    const float4 d = p[i + 3 * n4];
    float4 s;
    s.x = (a.x + b.x) + (c.x + d.x);
    s.y = (a.y + b.y) + (c.y + d.y);
    s.z = (a.z + b.z) + (c.z + d.z);
    s.w = (a.w + b.w) + (c.w + d.w);
    ((float4*)hidden)[i] = s;
  }
}

// ---------- Kernel D: MLP — 4 batches/wave, W1 reused 4x, DPP reduce -----
template <int CTRL>
__device__ __forceinline__ float dpp_add(float x) {
  const int y = __builtin_amdgcn_update_dpp(
      0, __float_as_int(x), CTRL, 0xf, 0xf, true);
  return x + __int_as_float(y);
}

__device__ __forceinline__ float wave_sum(float h) {
  h = dpp_add<0x111>(h);   // row_shr:1
  h = dpp_add<0x112>(h);   // row_shr:2
  h = dpp_add<0x114>(h);   // row_shr:4
  h = dpp_add<0x118>(h);   // row_shr:8
  h = dpp_add<0x142>(h);   // row_bcast:15
  h = dpp_add<0x143>(h);   // row_bcast:31  -> lane 63 holds full sum
  return h;
}

__global__ __launch_bounds__(256) void mlp_kernel(
    const float* __restrict__ hidden,
    const float* __restrict__ W1,
    const float* __restrict__ b1,
    const float* __restrict__ W2,
    float* __restrict__ out) {
  const int wave = threadIdx.x >> 6;
  const int lane = threadIdx.x & 63;
  const int b0   = (blockIdx.x * 4 + wave) * BW;
  const int j0   = blockIdx.y * JPER;

  // preload 4 hidden rows: k = lane + 64*i (600 = 64*9 + 24)
  float a[BW][10];
#pragma unroll
  for (int bb = 0; bb < BW; ++bb) {
    const float* __restrict__ hb = hidden + (size_t)(b0 + bb) * HID;
#pragma unroll
    for (int i = 0; i < 9; ++i) a[bb][i] = hb[lane + 64 * i];
    a[bb][9] = (lane < 24) ? hb[lane + 576] : 0.f;
  }

  float acc[BW] = {0.f, 0.f, 0.f, 0.f};

#pragma unroll 2
  for (int jj = 0; jj < JPER; ++jj) {
    const int j = j0 + jj;
    const float* __restrict__ wr = W1 + (size_t)j * HID;
    float d0 = 0.f, d1 = 0.f, d2 = 0.f, d3 = 0.f;
#pragma unroll
    for (int i = 0; i < 9; ++i) {
      const float w = wr[lane + 64 * i];
      d0 += a[0][i] * w;
      d1 += a[1][i] * w;
      d2 += a[2][i] * w;
      d3 += a[3][i] * w;
    }
    {
      const float w = (lane < 24) ? wr[lane + 576] : 0.f;
      d0 += a[0][9] * w;
      d1 += a[1][9] * w;
      d2 += a[2][9] * w;
      d3 += a[3][9] * w;
    }
    // 4 independent 6-step DPP chains (ILP hides DPP latency)
    d0 = wave_sum(d0); d1 = wave_sum(d1);
    d2 = wave_sum(d2); d3 = wave_sum(d3);
    // branch-free epilogue: only lane 63's acc is ever consumed
    const float b1j = b1[j];
    const float w2j = W2[j];
    acc[0] += fmaxf(d0 + b1j, 0.f) * w2j;
    acc[1] += fmaxf(d1 + b1j, 0.f) * w2j;
    acc[2] += fmaxf(d2 + b1j, 0.f) * w2j;
    acc[3] += fmaxf(d3 + b1j, 0.f) * w2j;
  }

  if (lane == 63) {
#pragma unroll
    for (int bb = 0; bb < BW; ++bb) atomicAdd(&out[b0 + bb], acc[bb]);
  }
}

extern "C" void kernel_launch(void* const* d_in, const int* in_sizes, int n_in,
                              void* d_out, int out_size, void* d_ws, size_t ws_size,
                              hipStream_t stream) {
  const int*   tokens = (const int*)  d_in[0];
  const float* lut    = (const float*)d_in[1];
  const float* slut   = (const float*)d_in[2];
  const float* W1     = (const float*)d_in[3];
  const float* b1     = (const float*)d_in[4];
  const float* W2     = (const float*)d_in[5];
  const float* b2     = (const float*)d_in[6];
  float* out = (float*)d_out;

  int*   sorted_g = (int*)d_ws;
  int*   nk_g     = (int*)((char*)d_ws + OFF_NK);
  float* hid4     = (float*)((char*)d_ws + OFF_HID4);
  float* hidden   = (float*)((char*)d_ws + OFF_HIDDEN);

  sort_kernel<<<BATCH, 256, 0, stream>>>(tokens, sorted_g, nk_g, out, b2);
  embed_gather_kernel<<<dim3(BATCH, NQ), 192, 0, stream>>>(
      sorted_g, nk_g, lut, slut, hid4);
  combine_kernel<<<(HIDDEN_ELEMS / 4 + 255) / 256, 256, 0, stream>>>(
      hid4, hidden);
  mlp_kernel<<<dim3(BATCH / (4 * BW), JCH), 256, 0, stream>>>(
      hidden, W1, b1, W2, out);
}